// Round 1
// baseline (316.895 us; speedup 1.0000x reference)
//
#include <hip/hip_runtime.h>
#include <stdint.h>

#define K_DIM 1024
#define N_DIM 1024
#define M_DIM 65536

typedef __bf16 bf16_t;
typedef __bf16 bf16x8 __attribute__((ext_vector_type(8)));
typedef float f32x4 __attribute__((ext_vector_type(4)));

#define GLOAD_LDS16(g, l) __builtin_amdgcn_global_load_lds( \
    (const __attribute__((address_space(1))) void*)(g),     \
    (__attribute__((address_space(3))) void*)(l), 16, 0, 0)

// ---------------------------------------------------------------------------
// Quantize-dequantize to bf16. Each thread handles 8 consecutive floats; a
// 32-element MX block = 4 adjacent lanes (shfl_xor reduce for block absmax).
// Replicates reference semantics: s = max(|block|)/7.5 (fp32 div), clamp 1e-30,
// y = x/s (fp32 div), round-to-nearest on the fp6 e2m3 grid with tie -> lower
// grid value (toward -inf), dequant q*s, then bf16 RNE.
// ---------------------------------------------------------------------------
__global__ __launch_bounds__(256) void quant_dequant_kernel(
    const float* __restrict__ in, bf16_t* __restrict__ out, long long nvec) {
  long long i = (long long)blockIdx.x * blockDim.x + threadIdx.x;
  long long stride = (long long)gridDim.x * blockDim.x;
  for (; i < nvec; i += stride) {
    long long base = i * 8;
    f32x4 v0 = *reinterpret_cast<const f32x4*>(in + base);
    f32x4 v1 = *reinterpret_cast<const f32x4*>(in + base + 4);
    float mx = 0.0f;
#pragma unroll
    for (int j = 0; j < 4; ++j) {
      mx = fmaxf(mx, fabsf(v0[j]));
      mx = fmaxf(mx, fabsf(v1[j]));
    }
    mx = fmaxf(mx, __shfl_xor(mx, 1));
    mx = fmaxf(mx, __shfl_xor(mx, 2));
    float s = fmaxf(mx / 7.5f, 1e-30f);
    bf16x8 o;
#pragma unroll
    for (int j = 0; j < 8; ++j) {
      float xv = (j < 4) ? v0[j] : v1[j - 4];
      float y = xv / s;                 // fp32 div, like reference
      float m = fabsf(y);
      float h, hinv;
      if (m < 2.0f)      { h = 0.125f; hinv = 8.0f; }
      else if (m < 4.0f) { h = 0.25f;  hinv = 4.0f; }
      else               { h = 0.5f;   hinv = 2.0f; }
      float n = m * hinv;               // exact (power-of-2 scale)
      float kf = floorf(n);
      float fr = n - kf;                // exact
      // tie (fr==0.5): positive -> keep lower magnitude; negative -> raise
      // magnitude (both = lower signed grid value, matching searchsorted ref)
      float up = (fr > 0.5f || (fr == 0.5f && y < 0.0f)) ? 1.0f : 0.0f;
      float q = fminf((kf + up) * h, 7.5f);
      o[j] = (bf16_t)(copysignf(q, y) * s);
    }
    *reinterpret_cast<bf16x8*>(out + base) = o;
  }
}

// ---------------------------------------------------------------------------
// bf16 GEMM, C = A * B^T + bias.  A: M x K row-major bf16, B: N x K row-major
// bf16 (so B^T layout — both operand fragments are 8 contiguous K elements).
// m97 structure: 128x128 tile, BK=32, 4 waves (2x2), 16x16x32 MFMA, staging
// via global_load_lds width=16.  LDS tiles [128][32] bf16 (64B rows) with XOR
// swizzle S' = S ^ ((R>>1)&3) on the 16B slot index: the 16-lane column-slice
// ds_read_b128 then covers all 32 banks (2 lanes/bank = free).  Source global
// addresses are inverse-swizzled so the linear global_load_lds dest matches
// (both-sides-or-neither rule).
// ---------------------------------------------------------------------------
__global__ __launch_bounds__(256) void mx_gemm(
    const bf16_t* __restrict__ A, const bf16_t* __restrict__ B,
    const float* __restrict__ bias, float* __restrict__ C) {
  __shared__ bf16_t sA[128 * 32];
  __shared__ bf16_t sB[128 * 32];

  const int tid = threadIdx.x;
  const int lane = tid & 63;
  const int wid = tid >> 6;
  const int wm = wid >> 1;  // 2x2 wave grid, each wave 64x64 out
  const int wn = wid & 1;

  // XCD-grouped mapping: 4096 blocks, 8 XCDs round-robin on raw blockIdx.
  // Each XCD owns a contiguous 64-wide m-panel range; within it, the 8
  // n-tiles of one m-panel are consecutive in time (A panel stays in L2,
  // B (2MB) is fully L2-resident).
  const int b = blockIdx.x;
  const int xcd = b & 7;
  const int t = b >> 3;
  const int m_tile = xcd * 64 + (t >> 3);  // [0,512)
  const int n_tile = t & 7;                // [0,8)

  const bf16_t* Abase = A + (size_t)m_tile * 128 * K_DIM;
  const bf16_t* Bbase = B + (size_t)n_tile * 128 * K_DIM;

  f32x4 acc[4][4];
#pragma unroll
  for (int i = 0; i < 4; ++i)
#pragma unroll
    for (int j = 0; j < 4; ++j)
      acc[i][j] = (f32x4)(0.0f);

  // Precompute staging source geometry (lane-constant across K steps).
  // chunk = j*4 + wid covers 0..7; byte p = chunk*1024 + lane*16;
  // R = p>>6 (row), T = (p>>4)&3 (stored slot); source col8 = T ^ ((R>>1)&3).
  int st_R[2], st_c8[2];
#pragma unroll
  for (int j = 0; j < 2; ++j) {
    int chunk = j * 4 + wid;
    int p = chunk * 1024 + lane * 16;
    int R = p >> 6;
    int T = (p >> 4) & 3;
    st_R[j] = R;
    st_c8[j] = (T ^ ((R >> 1) & 3)) << 3;
  }

  // Fragment read byte offsets (lane-dependent, K-step-invariant).
  const int S = lane >> 4;
  int rdA[4], rdB[4];
#pragma unroll
  for (int i = 0; i < 4; ++i) {
    int Ra = wm * 64 + i * 16 + (lane & 15);
    rdA[i] = Ra * 64 + ((S ^ ((Ra >> 1) & 3)) << 4);
    int Rb = wn * 64 + i * 16 + (lane & 15);
    rdB[i] = Rb * 64 + ((S ^ ((Rb >> 1) & 3)) << 4);
  }

  for (int kt = 0; kt < K_DIM / 32; ++kt) {
    const int k0 = kt * 32;
#pragma unroll
    for (int j = 0; j < 2; ++j) {
      int chunk = j * 4 + wid;
      GLOAD_LDS16(Abase + (size_t)st_R[j] * K_DIM + k0 + st_c8[j],
                  sA + chunk * 512);
      GLOAD_LDS16(Bbase + (size_t)st_R[j] * K_DIM + k0 + st_c8[j],
                  sB + chunk * 512);
    }
    __syncthreads();  // compiler drains vmcnt before barrier

    bf16x8 af[4], bv[4];
#pragma unroll
    for (int i = 0; i < 4; ++i) {
      af[i] = *reinterpret_cast<const bf16x8*>(
          reinterpret_cast<const char*>(sA) + rdA[i]);
      bv[i] = *reinterpret_cast<const bf16x8*>(
          reinterpret_cast<const char*>(sB) + rdB[i]);
    }
#pragma unroll
    for (int i = 0; i < 4; ++i)
#pragma unroll
      for (int j = 0; j < 4; ++j)
        acc[i][j] =
            __builtin_amdgcn_mfma_f32_16x16x32_bf16(af[i], bv[j], acc[i][j],
                                                    0, 0, 0);
    __syncthreads();
  }

  // Epilogue: C/D layout col = lane&15, row = (lane>>4)*4 + reg (m89).
  const int col0 = n_tile * 128 + wn * 64 + (lane & 15);
  const int row0 = m_tile * 128 + wm * 64 + ((lane >> 4) << 2);
#pragma unroll
  for (int j = 0; j < 4; ++j) {
    float bvv = bias[col0 + j * 16];
#pragma unroll
    for (int i = 0; i < 4; ++i) {
#pragma unroll
      for (int r = 0; r < 4; ++r) {
        C[(size_t)(row0 + i * 16 + r) * N_DIM + col0 + j * 16] =
            acc[i][j][r] + bvv;
      }
    }
  }
}

extern "C" void kernel_launch(void* const* d_in, const int* in_sizes, int n_in,
                              void* d_out, int out_size, void* d_ws,
                              size_t ws_size, hipStream_t stream) {
  const float* x = (const float*)d_in[0];     // 8*8192*1024 fp32
  const float* w = (const float*)d_in[1];     // 1024*1024 fp32
  const float* bias = (const float*)d_in[2];  // 1024 fp32
  float* out = (float*)d_out;                 // 65536*1024 fp32

  bf16_t* xd = (bf16_t*)d_ws;                        // 128 MB
  bf16_t* wd = xd + (size_t)M_DIM * K_DIM;           // +2 MB

  // 67,108,864 / 8 = 8,388,608 vec-items; grid-stride with 1M threads.
  quant_dequant_kernel<<<4096, 256, 0, stream>>>(x, xd,
                                                 (long long)M_DIM * K_DIM / 8);
  // 1,048,576 / 8 = 131,072 items = 512 blocks exactly.
  quant_dequant_kernel<<<512, 256, 0, stream>>>(w, wd,
                                                (long long)K_DIM * N_DIM / 8);

  mx_gemm<<<(M_DIM / 128) * (N_DIM / 128), 256, 0, stream>>>(xd, wd, bias,
                                                             out);
}

// Round 2
// 273.620 us; speedup vs baseline: 1.1582x; 1.1582x over previous
//
#include <hip/hip_runtime.h>
#include <stdint.h>

#define K_DIM 1024
#define N_DIM 1024
#define M_DIM 65536

typedef __bf16 bf16_t;
typedef __bf16 bf16x8 __attribute__((ext_vector_type(8)));
typedef float f32x4 __attribute__((ext_vector_type(4)));

#define GLOAD_LDS16(g, l) __builtin_amdgcn_global_load_lds( \
    (const __attribute__((address_space(1))) void*)(g),     \
    (__attribute__((address_space(3))) void*)(l), 16, 0, 0)

#define VMCNT(n) asm volatile("s_waitcnt vmcnt(%0)" ::"n"(n) : "memory")

// ---------------------------------------------------------------------------
// Quantize-dequantize to bf16 (unchanged from round 1 — passed, ~BW-bound).
// 8 floats/thread; 32-elem MX block = 4 adjacent lanes (shfl_xor absmax).
// Exact reference semantics: s = max/7.5 (fp32 div), clamp 1e-30, y = x/s,
// round-to-nearest on fp6 e2m3 grid with tie -> lower grid value.
// ---------------------------------------------------------------------------
__global__ __launch_bounds__(256) void quant_dequant_kernel(
    const float* __restrict__ in, bf16_t* __restrict__ out, long long nvec) {
  long long i = (long long)blockIdx.x * blockDim.x + threadIdx.x;
  long long stride = (long long)gridDim.x * blockDim.x;
  for (; i < nvec; i += stride) {
    long long base = i * 8;
    f32x4 v0 = *reinterpret_cast<const f32x4*>(in + base);
    f32x4 v1 = *reinterpret_cast<const f32x4*>(in + base + 4);
    float mx = 0.0f;
#pragma unroll
    for (int j = 0; j < 4; ++j) {
      mx = fmaxf(mx, fabsf(v0[j]));
      mx = fmaxf(mx, fabsf(v1[j]));
    }
    mx = fmaxf(mx, __shfl_xor(mx, 1));
    mx = fmaxf(mx, __shfl_xor(mx, 2));
    float s = fmaxf(mx / 7.5f, 1e-30f);
    bf16x8 o;
#pragma unroll
    for (int j = 0; j < 8; ++j) {
      float xv = (j < 4) ? v0[j] : v1[j - 4];
      float y = xv / s;  // fp32 div, like reference
      float m = fabsf(y);
      float h, hinv;
      if (m < 2.0f)      { h = 0.125f; hinv = 8.0f; }
      else if (m < 4.0f) { h = 0.25f;  hinv = 4.0f; }
      else               { h = 0.5f;   hinv = 2.0f; }
      float n = m * hinv;  // exact (power-of-2 scale)
      float kf = floorf(n);
      float fr = n - kf;   // exact
      float up = (fr > 0.5f || (fr == 0.5f && y < 0.0f)) ? 1.0f : 0.0f;
      float q = fminf((kf + up) * h, 7.5f);
      o[j] = (bf16_t)(copysignf(q, y) * s);
    }
    *reinterpret_cast<bf16x8*>(out + base) = o;
  }
}

// ---------------------------------------------------------------------------
// bf16 GEMM C = A * B^T + bias with counted-vmcnt deep pipeline (T3+T4+T5).
// Tile 256x256, BK=32, 512 threads = 8 waves (2M x 4N), per-wave out 128x64.
// LDS: 4-stage ring, stage = A[256][32] + B[256][32] bf16 = 32 KB, total 128K.
// Staging runs 3 K-tiles ahead; per K-tile exactly one s_waitcnt vmcnt(8)
// (tiles t+1,t+2 stay in flight) + one raw s_barrier (no vmcnt(0) drain).
// Race check: stage(t+3) overwrites buf[(t-1)&3]; issued only after iter-t
// barrier, which all waves reach only after finishing iter t-1's ds_reads.
// LDS swizzle: 16B slot' = slot ^ (row&3) (0 conflicts measured in round 1
// with this family); global source is inverse-pre-swizzled so the linear
// global_load_lds destination matches (both-sides-or-neither rule).
// ---------------------------------------------------------------------------
__global__ __launch_bounds__(512, 2) void mx_gemm(
    const bf16_t* __restrict__ A, const bf16_t* __restrict__ B,
    const float* __restrict__ bias, float* __restrict__ C) {
  __shared__ char lds[131072];

  const int tid = threadIdx.x;
  const int lane = tid & 63;
  const int wid = tid >> 6;
  const int wm = wid >> 2;  // 0..1  (128-row half)
  const int wn = wid & 3;   // 0..3  (64-col slice)

  // XCD-grouped mapping: 1024 blocks; xcd = b&7 matches HW round-robin.
  // Each XCD owns 32 contiguous m-tiles, n-inner -> A panel L2-reused 4x,
  // B (2 MB) L2-resident.
  const int b = blockIdx.x;
  const int xcd = b & 7;
  const int t = b >> 3;
  const int m_tile = xcd * 32 + (t >> 2);  // [0,256)
  const int n_tile = t & 3;                // [0,4)

  // Staging source: dest byte d = j*8192 + tid*16 -> row R = j*128 + (tid>>2),
  // physical slot T = tid&3; source logical slot = T ^ (R&3).
  const int R0 = tid >> 2;
  const int c0 = ((tid & 3) ^ ((tid >> 2) & 3)) * 8;  // elems
  const bf16_t* aS0 = A + (size_t)(m_tile * 256 + R0) * K_DIM + c0;
  const bf16_t* aS1 = aS0 + (size_t)128 * K_DIM;
  const bf16_t* bS0 = B + (size_t)(n_tile * 256 + R0) * K_DIM + c0;
  const bf16_t* bS1 = bS0 + (size_t)128 * K_DIM;
  const int dstOff = wid * 1024 + lane * 16;  // wave-uniform base + lane*16

  auto STAGE = [&](int u) {
    char* sbase = lds + (u & 3) * 32768;
    const int ko = u * 32;
    GLOAD_LDS16(aS0 + ko, sbase + dstOff);
    GLOAD_LDS16(aS1 + ko, sbase + 8192 + dstOff);
    GLOAD_LDS16(bS0 + ko, sbase + 16384 + dstOff);
    GLOAD_LDS16(bS1 + ko, sbase + 24576 + dstOff);
  };

  // Fragment read offsets. Row stride 64B, 4 slots/row; logical slot =
  // lane>>4, row&3 = lane&3 (rows step by 16) -> physical lane-only.
  const int ps = (((lane >> 4) ^ (lane & 3)) << 4);
  const int rowb = (lane & 15) * 64 + ps;
  const int aOff = wm * 8192 + rowb;          // + h*4096 + i*1024
  const int bOff = 16384 + wn * 4096 + rowb;  // + j*1024

  f32x4 acc[8][4];
#pragma unroll
  for (int i = 0; i < 8; ++i)
#pragma unroll
    for (int j = 0; j < 4; ++j) acc[i][j] = (f32x4)(0.0f);

  auto COMPUTE = [&](int u) {
    const char* sbase = lds + (u & 3) * 32768;
    bf16x8 bf[4], af[4];
#pragma unroll
    for (int j = 0; j < 4; ++j)
      bf[j] = *reinterpret_cast<const bf16x8*>(sbase + bOff + j * 1024);
#pragma unroll
    for (int i = 0; i < 4; ++i)
      af[i] = *reinterpret_cast<const bf16x8*>(sbase + aOff + i * 1024);
    __builtin_amdgcn_s_setprio(1);
#pragma unroll
    for (int i = 0; i < 4; ++i)
#pragma unroll
      for (int j = 0; j < 4; ++j)
        acc[i][j] = __builtin_amdgcn_mfma_f32_16x16x32_bf16(af[i], bf[j],
                                                            acc[i][j], 0, 0, 0);
    __builtin_amdgcn_s_setprio(0);
#pragma unroll
    for (int i = 0; i < 4; ++i)
      af[i] = *reinterpret_cast<const bf16x8*>(sbase + aOff + 4096 + i * 1024);
    __builtin_amdgcn_s_setprio(1);
#pragma unroll
    for (int i = 0; i < 4; ++i)
#pragma unroll
      for (int j = 0; j < 4; ++j)
        acc[4 + i][j] = __builtin_amdgcn_mfma_f32_16x16x32_bf16(
            af[i], bf[j], acc[4 + i][j], 0, 0, 0);
    __builtin_amdgcn_s_setprio(0);
  };

  // Prologue: 3 K-tiles in flight.
  STAGE(0);
  STAGE(1);
  STAGE(2);

  for (int kt = 0; kt < 29; ++kt) {
    VMCNT(8);  // own loads of tile kt landed; tiles kt+1,kt+2 stay in flight
    __builtin_amdgcn_s_barrier();
    __builtin_amdgcn_sched_barrier(0);
    STAGE(kt + 3);
    COMPUTE(kt);
  }
  VMCNT(8);
  __builtin_amdgcn_s_barrier();
  __builtin_amdgcn_sched_barrier(0);
  COMPUTE(29);
  VMCNT(4);
  __builtin_amdgcn_s_barrier();
  __builtin_amdgcn_sched_barrier(0);
  COMPUTE(30);
  VMCNT(0);
  __builtin_amdgcn_s_barrier();
  __builtin_amdgcn_sched_barrier(0);
  COMPUTE(31);

  // Epilogue. C/D layout: col = lane&15, row = (lane>>4)*4 + reg (m89).
  const int col0 = n_tile * 256 + wn * 64 + (lane & 15);
  const int row0 = m_tile * 256 + wm * 128 + ((lane >> 4) << 2);
#pragma unroll
  for (int j = 0; j < 4; ++j) {
    float bv = bias[col0 + j * 16];
#pragma unroll
    for (int m = 0; m < 8; ++m) {
#pragma unroll
      for (int r = 0; r < 4; ++r) {
        C[(size_t)(row0 + m * 16 + r) * N_DIM + col0 + j * 16] =
            acc[m][j][r] + bv;
      }
    }
  }
}

extern "C" void kernel_launch(void* const* d_in, const int* in_sizes, int n_in,
                              void* d_out, int out_size, void* d_ws,
                              size_t ws_size, hipStream_t stream) {
  const float* x = (const float*)d_in[0];     // 8*8192*1024 fp32
  const float* w = (const float*)d_in[1];     // 1024*1024 fp32
  const float* bias = (const float*)d_in[2];  // 1024 fp32
  float* out = (float*)d_out;                 // 65536*1024 fp32

  bf16_t* xd = (bf16_t*)d_ws;               // 128 MB
  bf16_t* wd = xd + (size_t)M_DIM * K_DIM;  // +2 MB

  quant_dequant_kernel<<<4096, 256, 0, stream>>>(x, xd,
                                                 (long long)M_DIM * K_DIM / 8);
  quant_dequant_kernel<<<512, 256, 0, stream>>>(w, wd,
                                                (long long)K_DIM * N_DIM / 8);

  mx_gemm<<<(M_DIM / 256) * (N_DIM / 256), 512, 0, stream>>>(xd, wd, bias,
                                                             out);
}

// Round 3
// 269.842 us; speedup vs baseline: 1.1744x; 1.0140x over previous
//
#include <hip/hip_runtime.h>
#include <stdint.h>

#define K_DIM 1024
#define N_DIM 1024
#define M_DIM 65536

typedef __bf16 bf16_t;
typedef __bf16 bf16x8 __attribute__((ext_vector_type(8)));
typedef float f32x4 __attribute__((ext_vector_type(4)));

#define GLOAD_LDS16(g, l) __builtin_amdgcn_global_load_lds( \
    (const __attribute__((address_space(1))) void*)(g),     \
    (__attribute__((address_space(3))) void*)(l), 16, 0, 0)

#define VMCNT(n) asm volatile("s_waitcnt vmcnt(%0)" ::"n"(n) : "memory")
#define LGKM(n) asm volatile("s_waitcnt lgkmcnt(%0)" ::"n"(n) : "memory")
#define SCHEDB() __builtin_amdgcn_sched_barrier(0)

// ---------------------------------------------------------------------------
// Quantize-dequantize to bf16 (unchanged — passed, near BW-bound).
// ---------------------------------------------------------------------------
__global__ __launch_bounds__(256) void quant_dequant_kernel(
    const float* __restrict__ in, bf16_t* __restrict__ out, long long nvec) {
  long long i = (long long)blockIdx.x * blockDim.x + threadIdx.x;
  long long stride = (long long)gridDim.x * blockDim.x;
  for (; i < nvec; i += stride) {
    long long base = i * 8;
    f32x4 v0 = *reinterpret_cast<const f32x4*>(in + base);
    f32x4 v1 = *reinterpret_cast<const f32x4*>(in + base + 4);
    float mx = 0.0f;
#pragma unroll
    for (int j = 0; j < 4; ++j) {
      mx = fmaxf(mx, fabsf(v0[j]));
      mx = fmaxf(mx, fabsf(v1[j]));
    }
    mx = fmaxf(mx, __shfl_xor(mx, 1));
    mx = fmaxf(mx, __shfl_xor(mx, 2));
    float s = fmaxf(mx / 7.5f, 1e-30f);
    bf16x8 o;
#pragma unroll
    for (int j = 0; j < 8; ++j) {
      float xv = (j < 4) ? v0[j] : v1[j - 4];
      float y = xv / s;  // fp32 div, like reference
      float m = fabsf(y);
      float h, hinv;
      if (m < 2.0f)      { h = 0.125f; hinv = 8.0f; }
      else if (m < 4.0f) { h = 0.25f;  hinv = 4.0f; }
      else               { h = 0.5f;   hinv = 2.0f; }
      float n = m * hinv;  // exact (power-of-2 scale)
      float kf = floorf(n);
      float fr = n - kf;   // exact
      float up = (fr > 0.5f || (fr == 0.5f && y < 0.0f)) ? 1.0f : 0.0f;
      float q = fminf((kf + up) * h, 7.5f);
      o[j] = (bf16_t)(copysignf(q, y) * s);
    }
    *reinterpret_cast<bf16x8*>(out + base) = o;
  }
}

// ---------------------------------------------------------------------------
// bf16 GEMM C = A*B^T + bias. 256x256 tile, BK=32, 8 waves (2M x 4N),
// 4-stage LDS ring (4 x 32KB), staging 3 K-tiles ahead, counted vmcnt.
// Round-3 changes vs round 2:
//  * swizzle restored to round-1 zero-conflict family: 16B slot' =
//    slot ^ ((row>>1)&3)  (round 2's (row&3) was a 4-way bank conflict).
//  * per-K-tile two-phase schedule with one-phase-ahead register pre-reads:
//      A(t): read af1(t) | STAGE(t+3) | lgkm(4) | 16 MFMA (af0 x bf)
//      B(t): vmcnt(8) | lgkm(0) | s_barrier | pre-read bf,af0(t+1) |
//            16 MFMA (af1 x bf)
//    so ds_reads are always in flight under the MFMA burst (T3 interleave),
//    loads never drain to vmcnt(0) in the loop (T4), setprio around MFMA (T5).
//  Safety: lgkm(0) before the barrier retires all reads of buf[t-1] before
//  any wave can issue STAGE(t+3) (which overwrites it); vmcnt(8)+barrier
//  precede any read of buf[t+1], so all waves' t+1 staging has landed.
// ---------------------------------------------------------------------------
__global__ __launch_bounds__(512, 2) void mx_gemm(
    const bf16_t* __restrict__ A, const bf16_t* __restrict__ B,
    const float* __restrict__ bias, float* __restrict__ C) {
  __shared__ char lds[131072];

  const int tid = threadIdx.x;
  const int lane = tid & 63;
  const int wid = tid >> 6;
  const int wm = wid >> 2;  // 0..1  (128-row half)
  const int wn = wid & 3;   // 0..3  (64-col slice)

  // XCD-grouped mapping (round 2, verified: A fetched ~once from HBM).
  const int b = blockIdx.x;
  const int xcd = b & 7;
  const int t = b >> 3;
  const int m_tile = xcd * 32 + (t >> 2);  // [0,256)
  const int n_tile = t & 3;                // [0,4)

  // Staging: dest byte d = region*8192 + tid*16 -> row R = tid>>2 (within
  // 128-row half), physical slot T = tid&3. Logical slot = T ^ ((R>>1)&3)
  // = (tid&3) ^ ((tid>>3)&3).
  const int R0 = tid >> 2;
  const int c0 = ((tid & 3) ^ ((tid >> 3) & 3)) * 8;  // elems
  const bf16_t* aS0 = A + (size_t)(m_tile * 256 + R0) * K_DIM + c0;
  const bf16_t* aS1 = aS0 + (size_t)128 * K_DIM;
  const bf16_t* bS0 = B + (size_t)(n_tile * 256 + R0) * K_DIM + c0;
  const bf16_t* bS1 = bS0 + (size_t)128 * K_DIM;
  const int dstOff = tid * 16;

#define STAGE(u)                                         \
  {                                                      \
    char* sb_ = lds + ((u) & 3) * 32768;                 \
    const int ko_ = (u) * 32;                            \
    GLOAD_LDS16(aS0 + ko_, sb_ + dstOff);                \
    GLOAD_LDS16(aS1 + ko_, sb_ + 8192 + dstOff);         \
    GLOAD_LDS16(bS0 + ko_, sb_ + 16384 + dstOff);        \
    GLOAD_LDS16(bS1 + ko_, sb_ + 24576 + dstOff);        \
  }

  // Fragment reads: row r = lane&15 (+16i), logical slot S = lane>>4,
  // physical slot = S ^ ((r>>1)&3) -> zero-conflict (8 distinct 16B slots
  // per 8 rows, 2 lanes/bank).  Row-offset terms (16i, 64*wn, 128*wm) are
  // multiples of 16 so (r>>1)&3 is lane-only.
  const int ps = (((lane >> 4) ^ ((lane >> 1) & 3)) << 4);
  const int rowb = (lane & 15) * 64 + ps;
  const int aOff = wm * 8192 + rowb;          // + half*4096 + i*1024
  const int bOff = 16384 + wn * 4096 + rowb;  // + j*1024

  f32x4 acc[8][4];
#pragma unroll
  for (int i = 0; i < 8; ++i)
#pragma unroll
    for (int j = 0; j < 4; ++j) acc[i][j] = (f32x4)(0.0f);

  bf16x8 bfA[4], bfB[4], afA[4], afB[4], af1[4];

#define PH_A(T, BF, AF0, DO_STG)                                          \
  {                                                                       \
    const char* sb_ = lds + ((T) & 3) * 32768;                            \
    _Pragma("unroll") for (int i = 0; i < 4; ++i) af1[i] =                \
        *reinterpret_cast<const bf16x8*>(sb_ + aOff + 4096 + i * 1024);   \
    if (DO_STG) STAGE((T) + 3);                                           \
    LGKM(4);                                                              \
    SCHEDB();                                                             \
    __builtin_amdgcn_s_setprio(1);                                        \
    _Pragma("unroll") for (int i = 0; i < 4; ++i)                         \
        _Pragma("unroll") for (int j = 0; j < 4; ++j) acc[i][j] =         \
            __builtin_amdgcn_mfma_f32_16x16x32_bf16(AF0[i], BF[j],        \
                                                    acc[i][j], 0, 0, 0);  \
    __builtin_amdgcn_s_setprio(0);                                        \
  }

#define PH_B(T, BF, NBF, NAF0, VMN, DO_PRE)                                  \
  {                                                                          \
    VMCNT(VMN);                                                              \
    LGKM(0);                                                                 \
    __builtin_amdgcn_s_barrier();                                            \
    SCHEDB();                                                                \
    if (DO_PRE) {                                                            \
      const char* sn_ = lds + (((T) + 1) & 3) * 32768;                       \
      _Pragma("unroll") for (int j = 0; j < 4; ++j) NBF[j] =                 \
          *reinterpret_cast<const bf16x8*>(sn_ + bOff + j * 1024);           \
      _Pragma("unroll") for (int i = 0; i < 4; ++i) NAF0[i] =                \
          *reinterpret_cast<const bf16x8*>(sn_ + aOff + i * 1024);           \
    }                                                                        \
    __builtin_amdgcn_s_setprio(1);                                           \
    _Pragma("unroll") for (int i = 0; i < 4; ++i)                            \
        _Pragma("unroll") for (int j = 0; j < 4; ++j) acc[4 + i][j] =        \
            __builtin_amdgcn_mfma_f32_16x16x32_bf16(af1[i], BF[j],           \
                                                    acc[4 + i][j], 0, 0, 0); \
    __builtin_amdgcn_s_setprio(0);                                           \
  }

  // Prologue: 3 K-tiles staged; wait tile 0; pre-read its bf/af0.
  STAGE(0);
  STAGE(1);
  STAGE(2);
  VMCNT(8);
  __builtin_amdgcn_s_barrier();
  SCHEDB();
#pragma unroll
  for (int j = 0; j < 4; ++j)
    bfA[j] = *reinterpret_cast<const bf16x8*>(lds + bOff + j * 1024);
#pragma unroll
  for (int i = 0; i < 4; ++i)
    afA[i] = *reinterpret_cast<const bf16x8*>(lds + aOff + i * 1024);

  for (int p = 0; p < 14; ++p) {
    const int u = 2 * p;
    PH_A(u, bfA, afA, true);
    PH_B(u, bfA, bfB, afB, 8, true);
    PH_A(u + 1, bfB, afB, true);
    PH_B(u + 1, bfB, bfA, afA, 8, true);
  }
  // t=28 (stages tile 31, the last)
  PH_A(28, bfA, afA, true);
  PH_B(28, bfA, bfB, afB, 8, true);
  // t=29: outstanding = tiles 30,31 (8 loads) -> wait 30's: vmcnt(4)
  PH_A(29, bfB, afB, false);
  PH_B(29, bfB, bfA, afA, 4, true);
  // t=30: outstanding = tile 31 (4 loads) -> vmcnt(0)
  PH_A(30, bfA, afA, false);
  PH_B(30, bfA, bfB, afB, 0, true);
  // t=31: final tile, no pre-read / no vmcnt / no barrier
  PH_A(31, bfB, afB, false);
  LGKM(0);
  SCHEDB();
#pragma unroll
  for (int i = 0; i < 4; ++i)
#pragma unroll
    for (int j = 0; j < 4; ++j)
      acc[4 + i][j] = __builtin_amdgcn_mfma_f32_16x16x32_bf16(
          af1[i], bfB[j], acc[4 + i][j], 0, 0, 0);

  // Epilogue. C/D layout: col = lane&15, row = (lane>>4)*4 + reg (m89).
  const int col0 = n_tile * 256 + wn * 64 + (lane & 15);
  const int row0 = m_tile * 256 + wm * 128 + ((lane >> 4) << 2);
#pragma unroll
  for (int j = 0; j < 4; ++j) {
    float bv = bias[col0 + j * 16];
#pragma unroll
    for (int m = 0; m < 8; ++m) {
#pragma unroll
      for (int r = 0; r < 4; ++r) {
        C[(size_t)(row0 + m * 16 + r) * N_DIM + col0 + j * 16] =
            acc[m][j][r] + bv;
      }
    }
  }
#undef STAGE
#undef PH_A
#undef PH_B
}

extern "C" void kernel_launch(void* const* d_in, const int* in_sizes, int n_in,
                              void* d_out, int out_size, void* d_ws,
                              size_t ws_size, hipStream_t stream) {
  const float* x = (const float*)d_in[0];     // 8*8192*1024 fp32
  const float* w = (const float*)d_in[1];     // 1024*1024 fp32
  const float* bias = (const float*)d_in[2];  // 1024 fp32
  float* out = (float*)d_out;                 // 65536*1024 fp32

  bf16_t* xd = (bf16_t*)d_ws;               // 128 MB
  bf16_t* wd = xd + (size_t)M_DIM * K_DIM;  // +2 MB

  quant_dequant_kernel<<<4096, 256, 0, stream>>>(x, xd,
                                                 (long long)M_DIM * K_DIM / 8);
  quant_dequant_kernel<<<512, 256, 0, stream>>>(w, wd,
                                                (long long)K_DIM * N_DIM / 8);

  mx_gemm<<<(M_DIM / 256) * (N_DIM / 256), 512, 0, stream>>>(xd, wd, bias,
                                                             out);
}